// Round 1
// baseline (1741.188 us; speedup 1.0000x reference)
//
#include <hip/hip_runtime.h>
#include <hip/hip_bf16.h>
#include <stdint.h>

#define NROWS 8192
#define DIM   1024

// ---------------------------------------------------------------------------
// Kernel 1: per-row sum of squares for anchor (a2) and negative (n2).
// One wave (64 lanes) per row; fp64 accumulate (memory-bound anyway) to
// minimize our rounding noise vs the reference.
// ---------------------------------------------------------------------------
__global__ __launch_bounds__(256) void sumsq_kernel(const float* __restrict__ A,
                                                    const float* __restrict__ B,
                                                    float* __restrict__ a2,
                                                    float* __restrict__ n2) {
    const float* src = (blockIdx.y == 0) ? A : B;
    float*       dst = (blockIdx.y == 0) ? a2 : n2;
    int row  = blockIdx.x * 4 + (threadIdx.x >> 6);
    int lane = threadIdx.x & 63;
    const float* p = src + (size_t)row * DIM;
    double s = 0.0;
#pragma unroll
    for (int q = 0; q < 4; ++q) {
        float4 v = *reinterpret_cast<const float4*>(p + (size_t)(lane + 64 * q) * 4);
        s += (double)v.x * v.x + (double)v.y * v.y + (double)v.z * v.z + (double)v.w * v.w;
    }
#pragma unroll
    for (int m = 32; m >= 1; m >>= 1) s += __shfl_xor(s, m, 64);
    if (lane == 0) dst[row] = (float)s;
}

// ---------------------------------------------------------------------------
// Kernel 2: fused GEMM (dot = A·B^T) + per-row argmax of the reference's
// exact fp32 expression  val = ((a2[i] + n2[j]) - 2*dot) * (1/1024).
// 128x128 tile, BK=16, 256 threads (16x16), 8x8 micro-tile with STRIDED
// row/col mapping: row = row0 + ty + 16*r, col = col0 + tx + 16*c.
// LDS tiles stored transposed [kk][row] (pad to 132) -> all fragment reads
// are broadcast or 16-consecutive-bank scalar reads (conflict-free).
// Merge across column-blocks via atomicMax on packed (val, ~col) keys:
// ties resolve to the LOWEST column index, matching jnp.argmax.
// ---------------------------------------------------------------------------
__global__ __launch_bounds__(256) void mse_argmax_kernel(
        const float* __restrict__ A, const float* __restrict__ B,
        const float* __restrict__ a2, const float* __restrict__ n2,
        unsigned long long* __restrict__ best) {
    __shared__ float As[16][132];
    __shared__ float Bs[16][132];

    const int tid = threadIdx.x;
    const int tx = tid & 15, ty = tid >> 4;
    const int row0 = blockIdx.x * 128;
    const int col0 = blockIdx.y * 128;

    float acc[8][8];
#pragma unroll
    for (int r = 0; r < 8; ++r)
#pragma unroll
        for (int c = 0; c < 8; ++c) acc[r][c] = 0.0f;

    for (int kt = 0; kt < DIM; kt += 16) {
        // Stage A/B tiles (128 rows x 16 floats) into transposed LDS layout.
#pragma unroll
        for (int p = 0; p < 2; ++p) {
            int li = p * 256 + tid;      // 0..511
            int r  = li >> 2;            // 0..127 (tile row)
            int s4 = li & 3;             // which float4 of the 16-wide slab
            float4 va = *reinterpret_cast<const float4*>(
                &A[(size_t)(row0 + r) * DIM + kt + s4 * 4]);
            float4 vb = *reinterpret_cast<const float4*>(
                &B[(size_t)(col0 + r) * DIM + kt + s4 * 4]);
            As[s4 * 4 + 0][r] = va.x; As[s4 * 4 + 1][r] = va.y;
            As[s4 * 4 + 2][r] = va.z; As[s4 * 4 + 3][r] = va.w;
            Bs[s4 * 4 + 0][r] = vb.x; Bs[s4 * 4 + 1][r] = vb.y;
            Bs[s4 * 4 + 2][r] = vb.z; Bs[s4 * 4 + 3][r] = vb.w;
        }
        __syncthreads();
#pragma unroll
        for (int kk = 0; kk < 16; ++kk) {
            float af[8], bf[8];
#pragma unroll
            for (int r = 0; r < 8; ++r) af[r] = As[kk][ty + 16 * r];
#pragma unroll
            for (int c = 0; c < 8; ++c) bf[c] = Bs[kk][tx + 16 * c];
#pragma unroll
            for (int r = 0; r < 8; ++r)
#pragma unroll
                for (int c = 0; c < 8; ++c) acc[r][c] = fmaf(af[r], bf[c], acc[r][c]);
        }
        __syncthreads();
    }

    // Epilogue: replicate the reference's fp32 rounding order exactly:
    //   t = (a2 + n2); t = t - 2*dot; val = t * (1/1024)   (exact pow2 scale)
#pragma unroll
    for (int r = 0; r < 8; ++r) {
        const int row = row0 + ty + 16 * r;
        const float arow = a2[row];
        unsigned long long bestk = 0ull;
#pragma unroll
        for (int c = 0; c < 8; ++c) {
            const int col = col0 + tx + 16 * c;
            float t = arow + n2[col];
            t = t - 2.0f * acc[r][c];
            const float val = t * (1.0f / 1024.0f);
            unsigned int b = __float_as_uint(val);
            b ^= (unsigned int)(((int)b >> 31) | 0x80000000);  // monotone map
            unsigned long long key =
                ((unsigned long long)b << 32) | (unsigned long long)(0xFFFFFFFFu - (unsigned)col);
            if (key > bestk) bestk = key;
        }
        // reduce across the 16 threads (tx lanes) sharing this row
#pragma unroll
        for (int m = 1; m < 16; m <<= 1) {
            unsigned long long other = __shfl_xor(bestk, m, 16);
            if (other > bestk) bestk = other;
        }
        if (tx == 0) atomicMax(&best[row], bestk);
    }
}

// ---------------------------------------------------------------------------
// Kernel 3: gather the winning negative row per anchor.
// ---------------------------------------------------------------------------
__global__ __launch_bounds__(256) void gather_kernel(
        const float* __restrict__ B,
        const unsigned long long* __restrict__ best,
        float* __restrict__ out) {
    const int row = blockIdx.x;
    const unsigned int col = 0xFFFFFFFFu - (unsigned int)(best[row] & 0xFFFFFFFFull);
    const float4* src = reinterpret_cast<const float4*>(B + (size_t)col * DIM);
    float4*       dst = reinterpret_cast<float4*>(out + (size_t)row * DIM);
    dst[threadIdx.x] = src[threadIdx.x];
}

extern "C" void kernel_launch(void* const* d_in, const int* in_sizes, int n_in,
                              void* d_out, int out_size, void* d_ws, size_t ws_size,
                              hipStream_t stream) {
    const float* anchor   = (const float*)d_in[0];
    const float* negative = (const float*)d_in[1];
    float* out = (float*)d_out;

    char* ws = (char*)d_ws;
    float* a2 = (float*)(ws);                        // 8192 * 4 B
    float* n2 = (float*)(ws + 32768);                // 8192 * 4 B
    unsigned long long* best = (unsigned long long*)(ws + 65536);  // 8192 * 8 B

    hipMemsetAsync(best, 0, NROWS * sizeof(unsigned long long), stream);

    sumsq_kernel<<<dim3(NROWS / 4, 2), 256, 0, stream>>>(anchor, negative, a2, n2);

    mse_argmax_kernel<<<dim3(NROWS / 128, NROWS / 128), 256, 0, stream>>>(
        anchor, negative, a2, n2, best);

    gather_kernel<<<NROWS, 256, 0, stream>>>(negative, best, out);
}

// Round 2
// 548.729 us; speedup vs baseline: 3.1731x; 3.1731x over previous
//
#include <hip/hip_runtime.h>
#include <hip/hip_bf16.h>
#include <stdint.h>

#define NROWS 8192
#define DIM   1024

typedef __attribute__((ext_vector_type(8))) short  short8;
typedef __attribute__((ext_vector_type(4))) float  f32x4;

// ---------------------------------------------------------------------------
// helpers
// ---------------------------------------------------------------------------
__device__ __forceinline__ unsigned int f32_key(float val) {
    unsigned int b = __float_as_uint(val);
    b ^= (unsigned int)(((int)b >> 31) | 0x80000000);  // monotone map
    return b;
}
__device__ __forceinline__ float key_val(unsigned long long k) {
    unsigned int b = (unsigned int)(k >> 32);
    b = (b & 0x80000000u) ? (b ^ 0x80000000u) : ~b;
    return __uint_as_float(b);
}
__device__ __forceinline__ unsigned short bf16_rne(float x) {
    unsigned int u = __float_as_uint(x);
    u += 0x7FFFu + ((u >> 16) & 1u);
    return (unsigned short)(u >> 16);
}
__device__ __forceinline__ void load_lds16(const void* g, void* l) {
    __builtin_amdgcn_global_load_lds((const __attribute__((address_space(1))) void*)g,
                                     (__attribute__((address_space(3))) void*)l, 16, 0, 0);
}

// ---------------------------------------------------------------------------
// per-row sum of squares (fp64 accumulate)
// ---------------------------------------------------------------------------
__global__ __launch_bounds__(256) void sumsq_kernel(const float* __restrict__ A,
                                                    const float* __restrict__ B,
                                                    float* __restrict__ a2,
                                                    float* __restrict__ n2) {
    const float* src = (blockIdx.y == 0) ? A : B;
    float*       dst = (blockIdx.y == 0) ? a2 : n2;
    int row  = blockIdx.x * 4 + (threadIdx.x >> 6);
    int lane = threadIdx.x & 63;
    const float* p = src + (size_t)row * DIM;
    double s = 0.0;
#pragma unroll
    for (int q = 0; q < 4; ++q) {
        float4 v = *reinterpret_cast<const float4*>(p + (size_t)(lane + 64 * q) * 4);
        s += (double)v.x * v.x + (double)v.y * v.y + (double)v.z * v.z + (double)v.w * v.w;
    }
#pragma unroll
    for (int m = 32; m >= 1; m >>= 1) s += __shfl_xor(s, m, 64);
    if (lane == 0) dst[row] = (float)s;
}

// ---------------------------------------------------------------------------
// split fp32 -> bf16 hi + bf16 lo   (x ~= hi + lo, residual ~2^-18 |x|)
// ---------------------------------------------------------------------------
__global__ __launch_bounds__(256) void split_kernel(const float* __restrict__ A,
                                                    const float* __restrict__ B,
                                                    unsigned short* __restrict__ Ah,
                                                    unsigned short* __restrict__ Al,
                                                    unsigned short* __restrict__ Bh,
                                                    unsigned short* __restrict__ Bl) {
    const float* src = blockIdx.y ? B : A;
    unsigned short* hi = blockIdx.y ? Bh : Ah;
    unsigned short* lo = blockIdx.y ? Bl : Al;
    size_t i = ((size_t)blockIdx.x * 256 + threadIdx.x) * 4;
    float4 v = *reinterpret_cast<const float4*>(src + i);
    float f[4] = {v.x, v.y, v.z, v.w};
    ushort4 h, l;
    unsigned short* hp = &h.x; unsigned short* lp = &l.x;
#pragma unroll
    for (int j = 0; j < 4; ++j) {
        unsigned short hb = bf16_rne(f[j]);
        float hf = __uint_as_float((unsigned int)hb << 16);
        hp[j] = hb;
        lp[j] = bf16_rne(f[j] - hf);
    }
    *reinterpret_cast<ushort4*>(hi + i) = h;
    *reinterpret_cast<ushort4*>(lo + i) = l;
}

// ---------------------------------------------------------------------------
// MFMA GEMM (split-bf16, 3 products) + per-64col-block top-2 key capture.
// 128x128 tile, BK=64, 4 waves (2x2), global_load_lds staging with
// pre-swizzled source chunks (chunk ^= row&7) so ds_read_b128 frag reads
// are bank-conflict-free (G4 pattern byte ^= (row&7)<<4).
// ---------------------------------------------------------------------------
__global__ __launch_bounds__(256, 2) void mfma_kernel(
        const unsigned short* __restrict__ Ah, const unsigned short* __restrict__ Al,
        const unsigned short* __restrict__ Bh, const unsigned short* __restrict__ Bl,
        const float* __restrict__ a2, const float* __restrict__ n2,
        unsigned long long* __restrict__ cand /* [NROWS][128][2] */) {
    __shared__ unsigned short lds[4][128 * 64];  // Ah, Al, Bh, Bl tiles (16 KB each)

    const int tid  = threadIdx.x;
    const int w    = tid >> 6;
    const int lane = tid & 63;
    const int row0 = blockIdx.x * 128;
    const int col0 = blockIdx.y * 128;
    const int wr = w >> 1, wc = w & 1;
    const int g = lane >> 4, m = lane & 15;

    f32x4 acc1[4][4], acc2[4][4];
#pragma unroll
    for (int r = 0; r < 4; ++r)
#pragma unroll
        for (int c = 0; c < 4; ++c) { acc1[r][c] = (f32x4)0.0f; acc2[r][c] = (f32x4)0.0f; }

    const unsigned short* gsrc[4] = {
        Ah + (size_t)row0 * DIM, Al + (size_t)row0 * DIM,
        Bh + (size_t)col0 * DIM, Bl + (size_t)col0 * DIM };

    for (int kt = 0; kt < DIM; kt += 64) {
        // ---- stage 4 tiles of [128 rows][64 bf16] via global_load_lds ----
#pragma unroll
        for (int t = 0; t < 4; ++t) {
            const unsigned short* gp = gsrc[t] + kt;
#pragma unroll
            for (int p = 0; p < 4; ++p) {
                int li  = p * 256 + tid;      // 0..1023
                int row = li >> 3;            // 0..127
                int ck  = li & 7;             // LDS 16B-chunk slot
                int cg  = ck ^ (row & 7);     // pre-swizzled source chunk
                load_lds16(gp + (size_t)row * DIM + cg * 8,
                           (char*)&lds[t][0] + (size_t)li * 16);
            }
        }
        __syncthreads();
        // ---- compute: 2 K=32 sub-steps, 3 MFMA products each ----
#pragma unroll
        for (int ks = 0; ks < 2; ++ks) {
            short8 afh[4], afl[4], bfh[4], bfl[4];
#pragma unroll
            for (int r = 0; r < 4; ++r) {
                int arow = wr * 64 + r * 16 + m;
                int ch   = (ks * 4 + g) ^ (arow & 7);
                afh[r] = *(const short8*)((const char*)&lds[0][0] + arow * 128 + ch * 16);
                afl[r] = *(const short8*)((const char*)&lds[1][0] + arow * 128 + ch * 16);
                int brow = wc * 64 + r * 16 + m;
                int ch2  = (ks * 4 + g) ^ (brow & 7);
                bfh[r] = *(const short8*)((const char*)&lds[2][0] + brow * 128 + ch2 * 16);
                bfl[r] = *(const short8*)((const char*)&lds[3][0] + brow * 128 + ch2 * 16);
            }
#pragma unroll
            for (int r = 0; r < 4; ++r)
#pragma unroll
                for (int c = 0; c < 4; ++c) {
                    acc1[r][c] = __builtin_amdgcn_mfma_f32_16x16x32_bf16(afh[r], bfh[c], acc1[r][c], 0, 0, 0);
                    acc2[r][c] = __builtin_amdgcn_mfma_f32_16x16x32_bf16(afh[r], bfl[c], acc2[r][c], 0, 0, 0);
                    acc2[r][c] = __builtin_amdgcn_mfma_f32_16x16x32_bf16(afl[r], bfh[c], acc2[r][c], 0, 0, 0);
                }
        }
        __syncthreads();
    }

    // ---- epilogue: reference-order val, per-row top-2 over this 64-col strip ----
    const int colbase = col0 + wc * 64;
    const int cb = blockIdx.y * 2 + wc;
#pragma unroll
    for (int r = 0; r < 4; ++r) {
#pragma unroll
        for (int j = 0; j < 4; ++j) {
            int row = row0 + wr * 64 + r * 16 + g * 4 + j;
            float arow = a2[row];
            unsigned long long k1 = 0ull, k2 = 0ull;
#pragma unroll
            for (int c = 0; c < 4; ++c) {
                int col = colbase + c * 16 + m;
                float dot = acc1[r][c][j] + acc2[r][c][j];
                float t = arow + n2[col];
                t = t - 2.0f * dot;
                float val = t * (1.0f / 1024.0f);
                unsigned long long key =
                    ((unsigned long long)f32_key(val) << 32) |
                    (unsigned long long)(0xFFFFFFFFu - (unsigned)col);
                if (key > k1) { k2 = k1; k1 = key; } else if (key > k2) { k2 = key; }
            }
#pragma unroll
            for (int s = 1; s < 16; s <<= 1) {
                unsigned long long o1 = __shfl_xor(k1, s, 64);
                unsigned long long o2 = __shfl_xor(k2, s, 64);
                unsigned long long hi = k1 > o1 ? k1 : o1;
                unsigned long long md = k1 > o1 ? o1 : k1;
                unsigned long long l2 = k2 > o2 ? k2 : o2;
                k1 = hi; k2 = md > l2 ? md : l2;
            }
            if (m == 0) {
                unsigned long long* p = &cand[((size_t)row * 128 + cb) * 2];
                p[0] = k1; p[1] = k2;
            }
        }
    }
}

// ---------------------------------------------------------------------------
// refine: per row, approx-max over 256 stored keys; recompute every candidate
// within DELTA (mse units) with round-1-identical fp32 arithmetic; pick winner.
// ---------------------------------------------------------------------------
#define DELTA 1e-4f
__global__ __launch_bounds__(256) void refine_kernel(
        const float* __restrict__ A, const float* __restrict__ B,
        const float* __restrict__ a2, const float* __restrict__ n2,
        const unsigned long long* __restrict__ cand,
        int* __restrict__ bestcol) {
    int row  = blockIdx.x * 4 + (threadIdx.x >> 6);
    int lane = threadIdx.x & 63;
    const unsigned long long* cp = cand + (size_t)row * 256;

    unsigned long long k[4];
#pragma unroll
    for (int q = 0; q < 4; ++q) k[q] = cp[lane + 64 * q];

    unsigned long long mx = k[0];
#pragma unroll
    for (int q = 1; q < 4; ++q) if (k[q] > mx) mx = k[q];
#pragma unroll
    for (int s = 1; s < 64; s <<= 1) {
        unsigned long long o = __shfl_xor(mx, s, 64);
        if (o > mx) mx = o;
    }
    const float thr = key_val(mx) - DELTA;

    unsigned long long bestk = 0ull;
    const float* ap = A + (size_t)row * DIM;
    const float arow = a2[row];
#pragma unroll
    for (int q = 0; q < 4; ++q) {
        if (key_val(k[q]) >= thr) {
            int col = (int)(0xFFFFFFFFu - (unsigned int)(k[q] & 0xFFFFFFFFull));
            const float* bp = B + (size_t)col * DIM;
            float acc = 0.0f;
            for (int kk = 0; kk < DIM; ++kk) acc = fmaf(ap[kk], bp[kk], acc);
            float t = arow + n2[col];
            t = t - 2.0f * acc;
            float val = t * (1.0f / 1024.0f);
            unsigned long long key =
                ((unsigned long long)f32_key(val) << 32) |
                (unsigned long long)(0xFFFFFFFFu - (unsigned)col);
            if (key > bestk) bestk = key;
        }
    }
#pragma unroll
    for (int s = 1; s < 64; s <<= 1) {
        unsigned long long o = __shfl_xor(bestk, s, 64);
        if (o > bestk) bestk = o;
    }
    if (lane == 0)
        bestcol[row] = (int)(0xFFFFFFFFu - (unsigned int)(bestk & 0xFFFFFFFFull));
}

__global__ __launch_bounds__(256) void gather_fast(const float* __restrict__ B,
                                                   const int* __restrict__ bestcol,
                                                   float* __restrict__ out) {
    int row = blockIdx.x;
    int col = bestcol[row];
    float4 v = reinterpret_cast<const float4*>(B + (size_t)col * DIM)[threadIdx.x];
    reinterpret_cast<float4*>(out + (size_t)row * DIM)[threadIdx.x] = v;
}

// ---------------------------------------------------------------------------
// fallback path (round-1, proven correct) if ws is too small
// ---------------------------------------------------------------------------
__global__ __launch_bounds__(256) void mse_argmax_kernel(
        const float* __restrict__ A, const float* __restrict__ B,
        const float* __restrict__ a2, const float* __restrict__ n2,
        unsigned long long* __restrict__ best) {
    __shared__ float As[16][132];
    __shared__ float Bs[16][132];
    const int tid = threadIdx.x;
    const int tx = tid & 15, ty = tid >> 4;
    const int row0 = blockIdx.x * 128;
    const int col0 = blockIdx.y * 128;
    float acc[8][8];
#pragma unroll
    for (int r = 0; r < 8; ++r)
#pragma unroll
        for (int c = 0; c < 8; ++c) acc[r][c] = 0.0f;
    for (int kt = 0; kt < DIM; kt += 16) {
#pragma unroll
        for (int p = 0; p < 2; ++p) {
            int li = p * 256 + tid;
            int r  = li >> 2;
            int s4 = li & 3;
            float4 va = *reinterpret_cast<const float4*>(&A[(size_t)(row0 + r) * DIM + kt + s4 * 4]);
            float4 vb = *reinterpret_cast<const float4*>(&B[(size_t)(col0 + r) * DIM + kt + s4 * 4]);
            As[s4 * 4 + 0][r] = va.x; As[s4 * 4 + 1][r] = va.y;
            As[s4 * 4 + 2][r] = va.z; As[s4 * 4 + 3][r] = va.w;
            Bs[s4 * 4 + 0][r] = vb.x; Bs[s4 * 4 + 1][r] = vb.y;
            Bs[s4 * 4 + 2][r] = vb.z; Bs[s4 * 4 + 3][r] = vb.w;
        }
        __syncthreads();
#pragma unroll
        for (int kk = 0; kk < 16; ++kk) {
            float af[8], bf[8];
#pragma unroll
            for (int r = 0; r < 8; ++r) af[r] = As[kk][ty + 16 * r];
#pragma unroll
            for (int c = 0; c < 8; ++c) bf[c] = Bs[kk][tx + 16 * c];
#pragma unroll
            for (int r = 0; r < 8; ++r)
#pragma unroll
                for (int c = 0; c < 8; ++c) acc[r][c] = fmaf(af[r], bf[c], acc[r][c]);
        }
        __syncthreads();
    }
#pragma unroll
    for (int r = 0; r < 8; ++r) {
        const int row = row0 + ty + 16 * r;
        const float arow = a2[row];
        unsigned long long bestk = 0ull;
#pragma unroll
        for (int c = 0; c < 8; ++c) {
            const int col = col0 + tx + 16 * c;
            float t = arow + n2[col];
            t = t - 2.0f * acc[r][c];
            const float val = t * (1.0f / 1024.0f);
            unsigned long long key =
                ((unsigned long long)f32_key(val) << 32) |
                (unsigned long long)(0xFFFFFFFFu - (unsigned)col);
            if (key > bestk) bestk = key;
        }
#pragma unroll
        for (int mm = 1; mm < 16; mm <<= 1) {
            unsigned long long other = __shfl_xor(bestk, mm, 16);
            if (other > bestk) bestk = other;
        }
        if (tx == 0) atomicMax(&best[row], bestk);
    }
}

__global__ __launch_bounds__(256) void gather_kernel(
        const float* __restrict__ B,
        const unsigned long long* __restrict__ best,
        float* __restrict__ out) {
    const int row = blockIdx.x;
    const unsigned int col = 0xFFFFFFFFu - (unsigned int)(best[row] & 0xFFFFFFFFull);
    const float4* src = reinterpret_cast<const float4*>(B + (size_t)col * DIM);
    float4*       dst = reinterpret_cast<float4*>(out + (size_t)row * DIM);
    dst[threadIdx.x] = src[threadIdx.x];
}

// ---------------------------------------------------------------------------
extern "C" void kernel_launch(void* const* d_in, const int* in_sizes, int n_in,
                              void* d_out, int out_size, void* d_ws, size_t ws_size,
                              hipStream_t stream) {
    const float* anchor   = (const float*)d_in[0];
    const float* negative = (const float*)d_in[1];
    float* out = (float*)d_out;
    char* ws = (char*)d_ws;

    const size_t plane = (size_t)NROWS * DIM * sizeof(unsigned short);  // 16 MB
    const size_t need  = 4 * plane + 3 * 65536;

    if (ws_size >= need) {
        unsigned short* Ah = (unsigned short*)(ws);
        unsigned short* Al = (unsigned short*)(ws + plane);
        unsigned short* Bh = (unsigned short*)(ws + 2 * plane);
        unsigned short* Bl = (unsigned short*)(ws + 3 * plane);
        float* a2 = (float*)(ws + 4 * plane);
        float* n2 = (float*)(ws + 4 * plane + 65536);
        int* bestcol = (int*)(ws + 4 * plane + 2 * 65536);
        unsigned long long* cand = (unsigned long long*)d_out;  // 16 MB < 32 MB, overwritten by gather

        sumsq_kernel<<<dim3(NROWS / 4, 2), 256, 0, stream>>>(anchor, negative, a2, n2);
        split_kernel<<<dim3(NROWS * DIM / 1024, 2), 256, 0, stream>>>(anchor, negative, Ah, Al, Bh, Bl);
        mfma_kernel<<<dim3(NROWS / 128, NROWS / 128), 256, 0, stream>>>(Ah, Al, Bh, Bl, a2, n2, cand);
        refine_kernel<<<NROWS / 4, 256, 0, stream>>>(anchor, negative, a2, n2, cand, bestcol);
        gather_fast<<<NROWS, 256, 0, stream>>>(negative, bestcol, out);
    } else {
        float* a2 = (float*)(ws);
        float* n2 = (float*)(ws + 32768);
        unsigned long long* best = (unsigned long long*)(ws + 65536);
        hipMemsetAsync(best, 0, NROWS * sizeof(unsigned long long), stream);
        sumsq_kernel<<<dim3(NROWS / 4, 2), 256, 0, stream>>>(anchor, negative, a2, n2);
        mse_argmax_kernel<<<dim3(NROWS / 128, NROWS / 128), 256, 0, stream>>>(anchor, negative, a2, n2, best);
        gather_kernel<<<NROWS, 256, 0, stream>>>(negative, best, out);
    }
}

// Round 3
// 367.449 us; speedup vs baseline: 4.7386x; 1.4933x over previous
//
#include <hip/hip_runtime.h>
#include <hip/hip_bf16.h>
#include <stdint.h>

#define NROWS 8192
#define DIM   1024

typedef __attribute__((ext_vector_type(8))) short  short8;
typedef __attribute__((ext_vector_type(4))) float  f32x4;

// ---------------------------------------------------------------------------
// helpers
// ---------------------------------------------------------------------------
__device__ __forceinline__ unsigned int f32_key(float val) {
    unsigned int b = __float_as_uint(val);
    b ^= (unsigned int)(((int)b >> 31) | 0x80000000);  // monotone map
    return b;
}
__device__ __forceinline__ float key_val(unsigned long long k) {
    unsigned int b = (unsigned int)(k >> 32);
    b = (b & 0x80000000u) ? (b ^ 0x80000000u) : ~b;
    return __uint_as_float(b);
}
__device__ __forceinline__ unsigned short bf16_rne(float x) {
    unsigned int u = __float_as_uint(x);
    u += 0x7FFFu + ((u >> 16) & 1u);
    return (unsigned short)(u >> 16);
}
__device__ __forceinline__ void load_lds16(const void* g, void* l) {
    __builtin_amdgcn_global_load_lds((const __attribute__((address_space(1))) void*)g,
                                     (__attribute__((address_space(3))) void*)l, 16, 0, 0);
}

// ---------------------------------------------------------------------------
// prep: fused per-row sum-of-squares (fp64 accumulate) + bf16-hi split.
// One wave per row; reads each input once.
// ---------------------------------------------------------------------------
__global__ __launch_bounds__(256) void prep_kernel(const float* __restrict__ A,
                                                   const float* __restrict__ B,
                                                   unsigned short* __restrict__ Ah,
                                                   unsigned short* __restrict__ Bh,
                                                   float* __restrict__ a2,
                                                   float* __restrict__ n2) {
    const float* src = blockIdx.y ? B : A;
    unsigned short* hi = blockIdx.y ? Bh : Ah;
    float* dst = blockIdx.y ? n2 : a2;
    int row  = blockIdx.x * 4 + (threadIdx.x >> 6);
    int lane = threadIdx.x & 63;
    const float* p = src + (size_t)row * DIM;
    double s = 0.0;
#pragma unroll
    for (int q = 0; q < 4; ++q) {
        float4 v = *reinterpret_cast<const float4*>(p + (size_t)(lane + 64 * q) * 4);
        s += (double)v.x * v.x + (double)v.y * v.y + (double)v.z * v.z + (double)v.w * v.w;
        ushort4 h;
        h.x = bf16_rne(v.x); h.y = bf16_rne(v.y);
        h.z = bf16_rne(v.z); h.w = bf16_rne(v.w);
        *reinterpret_cast<ushort4*>(hi + (size_t)row * DIM + (size_t)(lane + 64 * q) * 4) = h;
    }
#pragma unroll
    for (int m = 32; m >= 1; m >>= 1) s += __shfl_xor(s, m, 64);
    if (lane == 0) dst[row] = (float)s;
}

// ---------------------------------------------------------------------------
// MFMA screening GEMM (hi*hi only) + per-64col-block top-2 key capture.
// 128x128 tile, BK=64, 4 waves (2x2), global_load_lds with pre-swizzled
// source chunks (chunk ^= row&7) -> conflict-free ds_read_b128.
// Approx mse error sigma ~1e-4; refine_kernel recomputes exactly.
// ---------------------------------------------------------------------------
__global__ __launch_bounds__(256, 3) void mfma_kernel(
        const unsigned short* __restrict__ Ah,
        const unsigned short* __restrict__ Bh,
        const float* __restrict__ a2, const float* __restrict__ n2,
        unsigned long long* __restrict__ cand /* [NROWS][128][2] */) {
    __shared__ unsigned short lds[2][128 * 64];  // Ah, Bh tiles (16 KB each)

    const int tid  = threadIdx.x;
    const int w    = tid >> 6;
    const int lane = tid & 63;
    const int row0 = blockIdx.x * 128;
    const int col0 = blockIdx.y * 128;
    const int wr = w >> 1, wc = w & 1;
    const int g = lane >> 4, m = lane & 15;

    f32x4 acc[4][4];
#pragma unroll
    for (int r = 0; r < 4; ++r)
#pragma unroll
        for (int c = 0; c < 4; ++c) acc[r][c] = (f32x4)0.0f;

    const unsigned short* gA = Ah + (size_t)row0 * DIM;
    const unsigned short* gB = Bh + (size_t)col0 * DIM;

    for (int kt = 0; kt < DIM; kt += 64) {
        // ---- stage 2 tiles of [128 rows][64 bf16] via global_load_lds ----
#pragma unroll
        for (int p = 0; p < 4; ++p) {
            int li  = p * 256 + tid;      // 0..1023
            int row = li >> 3;            // 0..127
            int ck  = li & 7;             // LDS 16B-chunk slot
            int cg  = ck ^ (row & 7);     // pre-swizzled source chunk
            load_lds16(gA + (size_t)row * DIM + kt + cg * 8,
                       (char*)&lds[0][0] + (size_t)li * 16);
            load_lds16(gB + (size_t)row * DIM + kt + cg * 8,
                       (char*)&lds[1][0] + (size_t)li * 16);
        }
        __syncthreads();
#pragma unroll
        for (int ks = 0; ks < 2; ++ks) {
            short8 af[4], bf[4];
#pragma unroll
            for (int r = 0; r < 4; ++r) {
                int arow = wr * 64 + r * 16 + m;
                int ch   = (ks * 4 + g) ^ (arow & 7);
                af[r] = *(const short8*)((const char*)&lds[0][0] + arow * 128 + ch * 16);
                int brow = wc * 64 + r * 16 + m;
                int ch2  = (ks * 4 + g) ^ (brow & 7);
                bf[r] = *(const short8*)((const char*)&lds[1][0] + brow * 128 + ch2 * 16);
            }
#pragma unroll
            for (int r = 0; r < 4; ++r)
#pragma unroll
                for (int c = 0; c < 4; ++c)
                    acc[r][c] = __builtin_amdgcn_mfma_f32_16x16x32_bf16(af[r], bf[c], acc[r][c], 0, 0, 0);
        }
        __syncthreads();
    }

    // ---- epilogue: reference-order val, per-row top-2 over this 64-col strip ----
    const int colbase = col0 + wc * 64;
    const int cb = blockIdx.y * 2 + wc;
#pragma unroll
    for (int r = 0; r < 4; ++r) {
#pragma unroll
        for (int j = 0; j < 4; ++j) {
            int row = row0 + wr * 64 + r * 16 + g * 4 + j;
            float arow = a2[row];
            unsigned long long k1 = 0ull, k2 = 0ull;
#pragma unroll
            for (int c = 0; c < 4; ++c) {
                int col = colbase + c * 16 + m;
                float dot = acc[r][c][j];
                float t = arow + n2[col];
                t = t - 2.0f * dot;
                float val = t * (1.0f / 1024.0f);
                unsigned long long key =
                    ((unsigned long long)f32_key(val) << 32) |
                    (unsigned long long)(0xFFFFFFFFu - (unsigned)col);
                if (key > k1) { k2 = k1; k1 = key; } else if (key > k2) { k2 = key; }
            }
#pragma unroll
            for (int s = 1; s < 16; s <<= 1) {
                unsigned long long o1 = __shfl_xor(k1, s, 64);
                unsigned long long o2 = __shfl_xor(k2, s, 64);
                unsigned long long hi = k1 > o1 ? k1 : o1;
                unsigned long long md = k1 > o1 ? o1 : k1;
                unsigned long long l2 = k2 > o2 ? k2 : o2;
                k1 = hi; k2 = md > l2 ? md : l2;
            }
            if (m == 0) {
                unsigned long long* p = &cand[((size_t)row * 128 + cb) * 2];
                p[0] = k1; p[1] = k2;
            }
        }
    }
}

// ---------------------------------------------------------------------------
// refine: per row, approx-max over 256 stored keys; recompute every candidate
// within DELTA with round-1-identical fp32 arithmetic (serial fmaf, k asc).
// DELTA = 2e-3 ~ 14 sigma of the hi*hi screening error.
// ---------------------------------------------------------------------------
#define DELTA 2e-3f
__global__ __launch_bounds__(256) void refine_kernel(
        const float* __restrict__ A, const float* __restrict__ B,
        const float* __restrict__ a2, const float* __restrict__ n2,
        const unsigned long long* __restrict__ cand,
        int* __restrict__ bestcol) {
    int row  = blockIdx.x * 4 + (threadIdx.x >> 6);
    int lane = threadIdx.x & 63;
    const unsigned long long* cp = cand + (size_t)row * 256;

    unsigned long long k[4];
#pragma unroll
    for (int q = 0; q < 4; ++q) k[q] = cp[lane + 64 * q];

    unsigned long long mx = k[0];
#pragma unroll
    for (int q = 1; q < 4; ++q) if (k[q] > mx) mx = k[q];
#pragma unroll
    for (int s = 1; s < 64; s <<= 1) {
        unsigned long long o = __shfl_xor(mx, s, 64);
        if (o > mx) mx = o;
    }
    const float thr = key_val(mx) - DELTA;

    unsigned long long bestk = 0ull;
    const float* ap = A + (size_t)row * DIM;
    const float arow = a2[row];
#pragma unroll
    for (int q = 0; q < 4; ++q) {
        if (key_val(k[q]) >= thr) {
            int col = (int)(0xFFFFFFFFu - (unsigned int)(k[q] & 0xFFFFFFFFull));
            const float* bp = B + (size_t)col * DIM;
            float acc = 0.0f;
            for (int kk = 0; kk < DIM; ++kk) acc = fmaf(ap[kk], bp[kk], acc);
            float t = arow + n2[col];
            t = t - 2.0f * acc;
            float val = t * (1.0f / 1024.0f);
            unsigned long long key =
                ((unsigned long long)f32_key(val) << 32) |
                (unsigned long long)(0xFFFFFFFFu - (unsigned)col);
            if (key > bestk) bestk = key;
        }
    }
#pragma unroll
    for (int s = 1; s < 64; s <<= 1) {
        unsigned long long o = __shfl_xor(bestk, s, 64);
        if (o > bestk) bestk = o;
    }
    if (lane == 0)
        bestcol[row] = (int)(0xFFFFFFFFu - (unsigned int)(bestk & 0xFFFFFFFFull));
}

__global__ __launch_bounds__(256) void gather_fast(const float* __restrict__ B,
                                                   const int* __restrict__ bestcol,
                                                   float* __restrict__ out) {
    int row = blockIdx.x;
    int col = bestcol[row];
    float4 v = reinterpret_cast<const float4*>(B + (size_t)col * DIM)[threadIdx.x];
    reinterpret_cast<float4*>(out + (size_t)row * DIM)[threadIdx.x] = v;
}

// ---------------------------------------------------------------------------
// fallback path (round-1, proven correct) if ws is too small
// ---------------------------------------------------------------------------
__global__ __launch_bounds__(256) void sumsq_kernel(const float* __restrict__ A,
                                                    const float* __restrict__ B,
                                                    float* __restrict__ a2,
                                                    float* __restrict__ n2) {
    const float* src = (blockIdx.y == 0) ? A : B;
    float*       dst = (blockIdx.y == 0) ? a2 : n2;
    int row  = blockIdx.x * 4 + (threadIdx.x >> 6);
    int lane = threadIdx.x & 63;
    const float* p = src + (size_t)row * DIM;
    double s = 0.0;
#pragma unroll
    for (int q = 0; q < 4; ++q) {
        float4 v = *reinterpret_cast<const float4*>(p + (size_t)(lane + 64 * q) * 4);
        s += (double)v.x * v.x + (double)v.y * v.y + (double)v.z * v.z + (double)v.w * v.w;
    }
#pragma unroll
    for (int m = 32; m >= 1; m >>= 1) s += __shfl_xor(s, m, 64);
    if (lane == 0) dst[row] = (float)s;
}

__global__ __launch_bounds__(256) void mse_argmax_kernel(
        const float* __restrict__ A, const float* __restrict__ B,
        const float* __restrict__ a2, const float* __restrict__ n2,
        unsigned long long* __restrict__ best) {
    __shared__ float As[16][132];
    __shared__ float Bs[16][132];
    const int tid = threadIdx.x;
    const int tx = tid & 15, ty = tid >> 4;
    const int row0 = blockIdx.x * 128;
    const int col0 = blockIdx.y * 128;
    float acc[8][8];
#pragma unroll
    for (int r = 0; r < 8; ++r)
#pragma unroll
        for (int c = 0; c < 8; ++c) acc[r][c] = 0.0f;
    for (int kt = 0; kt < DIM; kt += 16) {
#pragma unroll
        for (int p = 0; p < 2; ++p) {
            int li = p * 256 + tid;
            int r  = li >> 2;
            int s4 = li & 3;
            float4 va = *reinterpret_cast<const float4*>(&A[(size_t)(row0 + r) * DIM + kt + s4 * 4]);
            float4 vb = *reinterpret_cast<const float4*>(&B[(size_t)(col0 + r) * DIM + kt + s4 * 4]);
            As[s4 * 4 + 0][r] = va.x; As[s4 * 4 + 1][r] = va.y;
            As[s4 * 4 + 2][r] = va.z; As[s4 * 4 + 3][r] = va.w;
            Bs[s4 * 4 + 0][r] = vb.x; Bs[s4 * 4 + 1][r] = vb.y;
            Bs[s4 * 4 + 2][r] = vb.z; Bs[s4 * 4 + 3][r] = vb.w;
        }
        __syncthreads();
#pragma unroll
        for (int kk = 0; kk < 16; ++kk) {
            float af[8], bf[8];
#pragma unroll
            for (int r = 0; r < 8; ++r) af[r] = As[kk][ty + 16 * r];
#pragma unroll
            for (int c = 0; c < 8; ++c) bf[c] = Bs[kk][tx + 16 * c];
#pragma unroll
            for (int r = 0; r < 8; ++r)
#pragma unroll
                for (int c = 0; c < 8; ++c) acc[r][c] = fmaf(af[r], bf[c], acc[r][c]);
        }
        __syncthreads();
    }
#pragma unroll
    for (int r = 0; r < 8; ++r) {
        const int row = row0 + ty + 16 * r;
        const float arow = a2[row];
        unsigned long long bestk = 0ull;
#pragma unroll
        for (int c = 0; c < 8; ++c) {
            const int col = col0 + tx + 16 * c;
            float t = arow + n2[col];
            t = t - 2.0f * acc[r][c];
            const float val = t * (1.0f / 1024.0f);
            unsigned long long key =
                ((unsigned long long)f32_key(val) << 32) |
                (unsigned long long)(0xFFFFFFFFu - (unsigned)col);
            if (key > bestk) bestk = key;
        }
#pragma unroll
        for (int mm = 1; mm < 16; mm <<= 1) {
            unsigned long long other = __shfl_xor(bestk, mm, 16);
            if (other > bestk) bestk = other;
        }
        if (tx == 0) atomicMax(&best[row], bestk);
    }
}

__global__ __launch_bounds__(256) void gather_kernel(
        const float* __restrict__ B,
        const unsigned long long* __restrict__ best,
        float* __restrict__ out) {
    const int row = blockIdx.x;
    const unsigned int col = 0xFFFFFFFFu - (unsigned int)(best[row] & 0xFFFFFFFFull);
    const float4* src = reinterpret_cast<const float4*>(B + (size_t)col * DIM);
    float4*       dst = reinterpret_cast<float4*>(out + (size_t)row * DIM);
    dst[threadIdx.x] = src[threadIdx.x];
}

// ---------------------------------------------------------------------------
extern "C" void kernel_launch(void* const* d_in, const int* in_sizes, int n_in,
                              void* d_out, int out_size, void* d_ws, size_t ws_size,
                              hipStream_t stream) {
    const float* anchor   = (const float*)d_in[0];
    const float* negative = (const float*)d_in[1];
    float* out = (float*)d_out;
    char* ws = (char*)d_ws;

    const size_t plane = (size_t)NROWS * DIM * sizeof(unsigned short);  // 16 MB
    const size_t need  = 2 * plane + 3 * 65536;

    if (ws_size >= need) {
        unsigned short* Ah = (unsigned short*)(ws);
        unsigned short* Bh = (unsigned short*)(ws + plane);
        float* a2 = (float*)(ws + 2 * plane);
        float* n2 = (float*)(ws + 2 * plane + 65536);
        int* bestcol = (int*)(ws + 2 * plane + 2 * 65536);
        unsigned long long* cand = (unsigned long long*)d_out;  // 16 MB < 32 MB, overwritten by gather

        prep_kernel<<<dim3(NROWS / 4, 2), 256, 0, stream>>>(anchor, negative, Ah, Bh, a2, n2);
        mfma_kernel<<<dim3(NROWS / 128, NROWS / 128), 256, 0, stream>>>(Ah, Bh, a2, n2, cand);
        refine_kernel<<<NROWS / 4, 256, 0, stream>>>(anchor, negative, a2, n2, cand, bestcol);
        gather_fast<<<NROWS, 256, 0, stream>>>(negative, bestcol, out);
    } else {
        float* a2 = (float*)(ws);
        float* n2 = (float*)(ws + 32768);
        unsigned long long* best = (unsigned long long*)(ws + 65536);
        hipMemsetAsync(best, 0, NROWS * sizeof(unsigned long long), stream);
        sumsq_kernel<<<dim3(NROWS / 4, 2), 256, 0, stream>>>(anchor, negative, a2, n2);
        mse_argmax_kernel<<<dim3(NROWS / 128, NROWS / 128), 256, 0, stream>>>(anchor, negative, a2, n2, best);
        gather_kernel<<<NROWS, 256, 0, stream>>>(negative, best, out);
    }
}